// Round 14
// baseline (310.623 us; speedup 1.0000x reference)
//
#include <hip/hip_runtime.h>
#include <stdint.h>

#define BATCH 4096
#define DIN 1024
#define DOUT 1024
#define NC 11          // GRID_SIZE + SPLINE_ORDER
#define KD 12288       // DIN * (1 + NC)
#define NKNOTS 15      // GRID_SIZE + 2*SPLINE_ORDER + 1

typedef __bf16 bf16x8 __attribute__((ext_vector_type(8)));
typedef float f32x4 __attribute__((ext_vector_type(4)));

__device__ __forceinline__ unsigned short f2bf(float f) {
    unsigned int u = __float_as_uint(f);
    unsigned int r = (u + 0x7FFFu + ((u >> 16) & 1u)) >> 16;
    return (unsigned short)r;
}

// ---------------------------------------------------------------------------
// Build A[b,:] = [ silu(u) | bsplines(silu(u)) ] in bf16, where
// u = x[b,:] (+ sum of np split-K partial slices — fuses the previous layer's
// split-K reduce into this pass).
// ---------------------------------------------------------------------------
__global__ __launch_bounds__(256) void build_A(
    const float* __restrict__ x, const float* __restrict__ P, int np,
    const float* __restrict__ grid, unsigned short* __restrict__ A) {
    __shared__ __align__(16) unsigned short lbs[256 * NC];
    const int tid = threadIdx.x;
    const int b  = blockIdx.x >> 2;
    const int i0 = (blockIdx.x & 3) * 256;
    const int i  = i0 + tid;

    float g[NKNOTS];
#pragma unroll
    for (int j = 0; j < NKNOTS; ++j) g[j] = grid[j];

    float xv = x[(size_t)b * DIN + i];
    for (int p = 0; p < np; ++p)
        xv += P[(size_t)p * BATCH * DIN + (size_t)b * DIN + i];
    const float s = xv / (1.f + __expf(-xv));   // silu

    float bs[14];
#pragma unroll
    for (int c = 0; c < 14; ++c) bs[c] = (s >= g[c] && s < g[c + 1]) ? 1.f : 0.f;
#pragma unroll
    for (int k = 1; k <= 3; ++k) {
        const float inv = (k == 1) ? 4.f : (k == 2) ? 2.f : (4.f / 3.f);
#pragma unroll
        for (int c = 0; c < 14 - k; ++c) {
            float left  = (s - g[c]) * inv;
            float right = (g[c + k + 1] - s) * inv;
            bs[c] = left * bs[c] + right * bs[c + 1];
        }
    }

    A[(size_t)b * KD + i] = f2bf(s);
#pragma unroll
    for (int c = 0; c < NC; ++c) lbs[tid * NC + c] = f2bf(bs[c]);
    __syncthreads();

    const uint4* src = (const uint4*)lbs;
    uint4* dst = (uint4*)(A + (size_t)b * KD + DIN + (size_t)i0 * NC);
    for (int j = tid; j < 352; j += 256) dst[j] = src[j];
}

// ---------------------------------------------------------------------------
// Build W[o, :] = [ base_w[o,:] | spline_w[o,:,:]*scaler[o,:] ] in bf16
// ---------------------------------------------------------------------------
__global__ __launch_bounds__(256) void build_W(
    const float* __restrict__ base_w, const float* __restrict__ spline_w,
    const float* __restrict__ scaler, unsigned short* __restrict__ W) {
    __shared__ __align__(16) unsigned short lw[256 * NC];
    const int tid = threadIdx.x;
    const int o  = blockIdx.x >> 2;
    const int i0 = (blockIdx.x & 3) * 256;
    const int i  = i0 + tid;
    const size_t oi = (size_t)o * DIN + i;

    const float sc = scaler[oi];
    W[(size_t)o * KD + i] = f2bf(base_w[oi]);
    const float* sw = spline_w + oi * NC;
#pragma unroll
    for (int c = 0; c < NC; ++c) lw[tid * NC + c] = f2bf(sw[c] * sc);
    __syncthreads();

    const uint4* src = (const uint4*)lw;
    uint4* dst = (uint4*)(W + (size_t)o * KD + DIN + (size_t)i0 * NC);
    for (int j = tid; j < 352; j += 256) dst[j] = src[j];
}

// ---------------------------------------------------------------------------
// GEMM (split-K): C = A[4096,12288] @ W[1024,12288]^T, f32 out.
// R14: register-subtile software pipeline on the R8/R13 4-phase skeleton.
// Phase p ds-loads the operand for phase p+1; MFMA uses operands loaded in
// p-1 (a full phase + barrier old -> compiler's auto lgkm waits pre-satisfied;
// DS pipe runs under the matrix pipe instead of serializing with it).
//   quadrants: q1(a0,b0) q2(a0,b1) q3(a1,b1) q4(a1,b0)
//   ds-loads:  ph1->b1(t), ph2->a1(t), ph3->none, ph4->a0,b0(t+1, buf nxt)
//   stages:    ph1->Bh0', ph2->Bh1', ph3->Ah1', ph4->Ah0''(t+2; region free)
//   waits:     vmcnt(4) at ph1/ph3/ph4 closes (retired halves >=2 phases old;
//              steady state 3 halves in flight). 4 barriers/tile, no manual
//              lgkmcnt. T2 XOR-swizzle, n-grouped block map, setprio on MFMA.
// ---------------------------------------------------------------------------
#define BM 256
#define BN 256
#define BK 64

#define LOADAF(AF, BASE)                                                       \
    _Pragma("unroll")                                                          \
    for (int fm = 0; fm < 4; ++fm)                                             \
        _Pragma("unroll")                                                      \
        for (int ks = 0; ks < 2; ++ks)                                         \
            AF[fm][ks] = *(const bf16x8*)&(BASE)[(wm * 64 + fm * 16 + rof) * 64 + \
                                                 (((ks * 4 + kcol) ^ xr) * 8)];

#define LOADBF(BF, BASE)                                                       \
    _Pragma("unroll")                                                          \
    for (int fn = 0; fn < 2; ++fn)                                             \
        _Pragma("unroll")                                                      \
        for (int ks = 0; ks < 2; ++ks)                                         \
            BF[fn][ks] = *(const bf16x8*)&(BASE)[(wn * 32 + fn * 16 + rof) * 64 + \
                                                 (((ks * 4 + kcol) ^ xr) * 8)];

#define MFMA16(AF, BF, RO, CO)                                                 \
    __builtin_amdgcn_s_setprio(1);                                             \
    _Pragma("unroll")                                                          \
    for (int ks = 0; ks < 2; ++ks)                                             \
        _Pragma("unroll")                                                      \
        for (int fm = 0; fm < 4; ++fm)                                         \
            _Pragma("unroll")                                                  \
            for (int fn = 0; fn < 2; ++fn)                                     \
                acc[(RO) + fm][(CO) + fn] =                                    \
                    __builtin_amdgcn_mfma_f32_16x16x32_bf16(                   \
                        AF[fm][ks], BF[fn][ks], acc[(RO) + fm][(CO) + fn], 0, 0, 0); \
    __builtin_amdgcn_s_setprio(0);

#define SBAR  __builtin_amdgcn_s_barrier()
#define SCHED __builtin_amdgcn_sched_barrier(0)

__global__ __launch_bounds__(512, 2) void gemm_kan(
    const unsigned short* __restrict__ A,
    const unsigned short* __restrict__ W,
    float* __restrict__ C, float* __restrict__ Part,
    int kspl, int ktper) {
    __shared__ unsigned short As[2 * 2 * 8192];   // [buf][half][128*64] = 64KB
    __shared__ unsigned short Bs[2 * 2 * 8192];   // 64KB (128KB total)

    const int tid  = threadIdx.x;
    const int wave = tid >> 6;
    const int lane = tid & 63;
    const int per = 16 * kspl;                   // blocks per n-tile
    const int n0  = (blockIdx.x / per) * BN;
    const int r   = blockIdx.x % per;
    const int ksp = r % kspl;
    const int m0  = (r / kspl) * BM;
    const int wm = wave >> 2;                    // 0..1
    const int wn = wave & 3;                     // 0..3

    // staging: linear LDS dest (lane*16B); global source col pre-swizzled so
    // LDS[row][c'] holds global col c' ^ ((row&7)<<4)  (T2, rule #21)
    const int srow = lane >> 3;
    const int scol = 8 * ((lane & 7) ^ (lane >> 3));
    const int kbase = ksp * ktper * BK;

    f32x4 acc[8][4];
#pragma unroll
    for (int a = 0; a < 8; ++a)
#pragma unroll
        for (int b = 0; b < 4; ++b) acc[a][b] = (f32x4){0.f, 0.f, 0.f, 0.f};

    auto stageA = [&](int buf, int h, int kt) {
        const int kk = kbase + kt * BK + scol;
#pragma unroll
        for (int c = 0; c < 2; ++c) {
            const int chunk = wave * 2 + c;      // 0..15 (8-row chunks in half)
            const unsigned short* ga =
                A + (size_t)(m0 + h * 128 + chunk * 8 + srow) * KD + kk;
            __builtin_amdgcn_global_load_lds(
                (const __attribute__((address_space(1))) unsigned int*)ga,
                (__attribute__((address_space(3))) unsigned int*)
                    &As[buf * 16384 + h * 8192 + chunk * 512], 16, 0, 0);
        }
    };
    auto stageB = [&](int buf, int h, int kt) {
        const int kk = kbase + kt * BK + scol;
#pragma unroll
        for (int c = 0; c < 2; ++c) {
            const int chunk = wave * 2 + c;
            const unsigned short* gb =
                W + (size_t)(n0 + h * 128 + chunk * 8 + srow) * KD + kk;
            __builtin_amdgcn_global_load_lds(
                (const __attribute__((address_space(1))) unsigned int*)gb,
                (__attribute__((address_space(3))) unsigned int*)
                    &Bs[buf * 16384 + h * 8192 + chunk * 512], 16, 0, 0);
        }
    };

    const int rof  = lane & 15;
    const int xr   = lane & 7;
    const int kcol = lane >> 4;

    bf16x8 a0[4][2], a1[4][2], b0[2][2], b1[2][2];

    // prologue: stage all of tile 0 + Ah0(1); publish tile 0 (vmcnt(2) keeps
    // Ah0(1) in flight); pre-load q1(0)'s registers.
    stageA(0, 0, 0); stageB(0, 0, 0); stageB(0, 1, 0); stageA(0, 1, 0);
    if (ktper > 1) stageA(1, 0, 1);
    if (ktper > 1) { asm volatile("s_waitcnt vmcnt(2)" ::: "memory"); }
    else           { asm volatile("s_waitcnt vmcnt(0)" ::: "memory"); }
    SBAR; SCHED;
    LOADAF(a0, &As[0]);
    LOADBF(b0, &Bs[0]);

    for (int t = 0; t < ktper; ++t) {
        const int cur = t & 1;
        const int nxt = cur ^ 1;
        const bool pf = (t + 1 < ktper);
        const unsigned short* Ab  = &As[cur * 16384];
        const unsigned short* Bb  = &Bs[cur * 16384];
        const unsigned short* Abn = &As[nxt * 16384];
        const unsigned short* Bbn = &Bs[nxt * 16384];

        // ---- ph1: q1 MFMA (a0,b0); ds-load b1<-Bh1(t) for ph2; stage Bh0'.
        // close: vmcnt(4) retires Ah1(t) (staged ph3(t-1), age 2) for ph2.
        if (pf) stageB(nxt, 0, t + 1);
        LOADBF(b1, Bb + 8192);
        MFMA16(a0, b0, 0, 0);
        SCHED;
        if (pf) { asm volatile("s_waitcnt vmcnt(4)" ::: "memory"); }
        else    { asm volatile("s_waitcnt vmcnt(0)" ::: "memory"); }
        SBAR; SCHED;

        // ---- ph2: q2 (a0,b1); ds-load a1<-Ah1(t) for ph3; stage Bh1'.
        if (pf) stageB(nxt, 1, t + 1);
        LOADAF(a1, Ab + 8192);
        MFMA16(a0, b1, 0, 2);
        SCHED; SBAR; SCHED;

        // ---- ph3: q3 (a1,b1); no ds-load; stage Ah1'.
        // close: vmcnt(4) retires Ah0(t+1)[ph4(t-1), age 4], Bh0(t+1)[ph1, 2]
        // for ph4's cross-buffer loads.
        if (pf) stageA(nxt, 1, t + 1);
        MFMA16(a1, b1, 4, 2);
        SCHED;
        if (pf) { asm volatile("s_waitcnt vmcnt(4)" ::: "memory"); }
        else    { asm volatile("s_waitcnt vmcnt(0)" ::: "memory"); }
        SBAR; SCHED;

        // ---- ph4: q4 (a1,b0); ds-load a0,b0 <- tile t+1 half0 (buf nxt)
        // for ph1(t+1); stage Ah0(t+2) into buf cur (region free since
        // ph4(t-1)). close: retire Bh1(t+1) (staged ph2, age 2) for next ph1.
        MFMA16(a1, b0, 4, 0);
        if (t + 2 < ktper) stageA(cur, 0, t + 2);
        if (pf) { LOADAF(a0, Abn); LOADBF(b0, Bbn); }
        SCHED;
        if (t + 2 < ktper) { asm volatile("s_waitcnt vmcnt(4)" ::: "memory"); }
        else if (pf)       { asm volatile("s_waitcnt vmcnt(2)" ::: "memory"); }
        else               { asm volatile("s_waitcnt vmcnt(0)" ::: "memory"); }
        SBAR; SCHED;
    }

    // epilogue: C/D layout col=lane&15, row=(lane>>4)*4+reg
    float* Cp = (ksp == 0) ? C : (Part + (size_t)(ksp - 1) * BATCH * DOUT);
    const int crow = (lane >> 4) * 4;
    const int ccol = lane & 15;
#pragma unroll
    for (int H = 0; H < 2; ++H)
#pragma unroll
        for (int fm = 0; fm < 4; ++fm)
#pragma unroll
            for (int F = 0; F < 2; ++F)
#pragma unroll
                for (int fn = 0; fn < 2; ++fn) {
                    const int row = m0 + H * 128 + wm * 64 + fm * 16 + crow;
                    const int col = n0 + F * 128 + wn * 32 + fn * 16 + ccol;
#pragma unroll
                    for (int rr = 0; rr < 4; ++rr)
                        Cp[(size_t)(row + rr) * DOUT + col] =
                            acc[H * 4 + fm][F * 2 + fn][rr];
                }
}

// ---------------------------------------------------------------------------
// X += sum of np partial slices, float4 vectorized (final layer only)
// ---------------------------------------------------------------------------
__global__ __launch_bounds__(256) void reduce_add(
    const float* __restrict__ P, float* __restrict__ X, int np) {
    const size_t i = ((size_t)blockIdx.x * 256 + threadIdx.x) * 4;
    f32x4 a = *(const f32x4*)(X + i);
    for (int p = 0; p < np; ++p)
        a = a + *(const f32x4*)(P + (size_t)p * BATCH * DOUT + i);
    *(f32x4*)(X + i) = a;
}

// ---------------------------------------------------------------------------
extern "C" void kernel_launch(void* const* d_in, const int* in_sizes, int n_in,
                              void* d_out, int out_size, void* d_ws, size_t ws_size,
                              hipStream_t stream) {
    const float* x        = (const float*)d_in[0];
    const float* base_w   = (const float*)d_in[1];
    const float* spline_w = (const float*)d_in[2];
    const float* scaler   = (const float*)d_in[3];
    const float* grid     = (const float*)d_in[4];
    float* out = (float*)d_out;

    char* ws = (char*)d_ws;
    unsigned short* Abf = (unsigned short*)ws;                       // 100,663,296 B
    unsigned short* Wbf = (unsigned short*)(ws + 100663296);         //  25,165,824 B
    float* xtmp = (float*)(ws + 100663296 + 25165824);               //  16,777,216 B
    float* Part = (float*)(ws + 100663296 + 25165824 + 16777216);    // up to 3x16.8MB

    // kspl=4 needs 3 partial buffers; fall back if scratch is short.
    const size_t base_need = 100663296u + 25165824u + 16777216u;
    const int kspl = (ws_size >= base_need + 3u * 16777216u) ? 4 : 2;
    const int ktper = (KD / BK) / kspl;

    for (int layer = 0; layer < 2; ++layer) {
        const float* xin = (layer == 0) ? x : xtmp;
        float* xout      = (layer == 0) ? xtmp : out;
        build_W<<<4096, 256, 0, stream>>>(base_w + (size_t)layer * DOUT * DIN,
                                          spline_w + (size_t)layer * DOUT * DIN * NC,
                                          scaler + (size_t)layer * DOUT * DIN, Wbf);
        // layer 1's build_A fuses the layer-0 split-K reduce (np = kspl-1)
        build_A<<<16384, 256, 0, stream>>>(xin, Part, (layer == 0) ? 0 : kspl - 1,
                                           grid, Abf);
        gemm_kan<<<64 * kspl, 512, 0, stream>>>(Abf, Wbf, xout, Part, kspl, ktper);
    }
    reduce_add<<<BATCH * DOUT / 1024, 256, 0, stream>>>(Part, out, kspl - 1);
}

// Round 15
// 295.530 us; speedup vs baseline: 1.0511x; 1.0511x over previous
//
#include <hip/hip_runtime.h>
#include <stdint.h>

#define BATCH 4096
#define DIN 1024
#define DOUT 1024
#define NC 11          // GRID_SIZE + SPLINE_ORDER
#define KD 12288       // DIN * (1 + NC)
#define NKNOTS 15      // GRID_SIZE + 2*SPLINE_ORDER + 1

typedef __bf16 bf16x8 __attribute__((ext_vector_type(8)));
typedef float f32x4 __attribute__((ext_vector_type(4)));

__device__ __forceinline__ unsigned short f2bf(float f) {
    unsigned int u = __float_as_uint(f);
    unsigned int r = (u + 0x7FFFu + ((u >> 16) & 1u)) >> 16;
    return (unsigned short)r;
}

// ---------------------------------------------------------------------------
// Build A[b,:] = [ silu(u) | bsplines(silu(u)) ] in bf16, where
// u = x[b,:] (+ sum of np split-K partial slices — fuses the previous layer's
// split-K reduce into this pass).
// ---------------------------------------------------------------------------
__global__ __launch_bounds__(256) void build_A(
    const float* __restrict__ x, const float* __restrict__ P, int np,
    const float* __restrict__ grid, unsigned short* __restrict__ A) {
    __shared__ __align__(16) unsigned short lbs[256 * NC];
    const int tid = threadIdx.x;
    const int b  = blockIdx.x >> 2;
    const int i0 = (blockIdx.x & 3) * 256;
    const int i  = i0 + tid;

    float g[NKNOTS];
#pragma unroll
    for (int j = 0; j < NKNOTS; ++j) g[j] = grid[j];

    float xv = x[(size_t)b * DIN + i];
    for (int p = 0; p < np; ++p)
        xv += P[(size_t)p * BATCH * DIN + (size_t)b * DIN + i];
    const float s = xv / (1.f + __expf(-xv));   // silu

    float bs[14];
#pragma unroll
    for (int c = 0; c < 14; ++c) bs[c] = (s >= g[c] && s < g[c + 1]) ? 1.f : 0.f;
#pragma unroll
    for (int k = 1; k <= 3; ++k) {
        const float inv = (k == 1) ? 4.f : (k == 2) ? 2.f : (4.f / 3.f);
#pragma unroll
        for (int c = 0; c < 14 - k; ++c) {
            float left  = (s - g[c]) * inv;
            float right = (g[c + k + 1] - s) * inv;
            bs[c] = left * bs[c] + right * bs[c + 1];
        }
    }

    A[(size_t)b * KD + i] = f2bf(s);
#pragma unroll
    for (int c = 0; c < NC; ++c) lbs[tid * NC + c] = f2bf(bs[c]);
    __syncthreads();

    const uint4* src = (const uint4*)lbs;
    uint4* dst = (uint4*)(A + (size_t)b * KD + DIN + (size_t)i0 * NC);
    for (int j = tid; j < 352; j += 256) dst[j] = src[j];
}

// ---------------------------------------------------------------------------
// Build W[o, :] = [ base_w[o,:] | spline_w[o,:,:]*scaler[o,:] ] in bf16
// ---------------------------------------------------------------------------
__global__ __launch_bounds__(256) void build_W(
    const float* __restrict__ base_w, const float* __restrict__ spline_w,
    const float* __restrict__ scaler, unsigned short* __restrict__ W) {
    __shared__ __align__(16) unsigned short lw[256 * NC];
    const int tid = threadIdx.x;
    const int o  = blockIdx.x >> 2;
    const int i0 = (blockIdx.x & 3) * 256;
    const int i  = i0 + tid;
    const size_t oi = (size_t)o * DIN + i;

    const float sc = scaler[oi];
    W[(size_t)o * KD + i] = f2bf(base_w[oi]);
    const float* sw = spline_w + oi * NC;
#pragma unroll
    for (int c = 0; c < NC; ++c) lw[tid * NC + c] = f2bf(sw[c] * sc);
    __syncthreads();

    const uint4* src = (const uint4*)lw;
    uint4* dst = (uint4*)(W + (size_t)o * KD + DIN + (size_t)i0 * NC);
    for (int j = tid; j < 352; j += 256) dst[j] = src[j];
}

// ---------------------------------------------------------------------------
// GEMM (split-K): C = A[4096,12288] @ W[1024,12288]^T, f32 out.
// R15 = R13 champion schedule MINUS manual lgkmcnt forcing.
// The blanket lgkmcnt(0) before each MFMA cluster made every wave drain all
// 12 ds_reads before its first MFMA -> chip-wide DS-burst/MFMA-burst
// alternation (observed 5100cy/K-tile = DS 2816 + MFMA 2484, zero overlap).
// Our ds_reads are C++ vector loads (NOT inline asm), so the compiler tracks
// them and emits fine-grained lgkmcnt(N) per MFMA (m97 evidence) — first
// MFMA starts when ITS operands land; later reads drain under earlier MFMAs.
// Kept unchanged: all barriers, counted vmcnt ledger (first-need staging,
// all waits retire >=2-phase-old loads), sched_barrier(0) after every
// publication barrier (stops ds_reads hoisting above it — compiler cannot
// see gload_lds->LDS deps), setprio, T2 XOR-swizzle, n-grouped block map.
// ---------------------------------------------------------------------------
#define BM 256
#define BN 256
#define BK 64

#define LOADAF(AF, BASE)                                                       \
    _Pragma("unroll")                                                          \
    for (int fm = 0; fm < 4; ++fm)                                             \
        _Pragma("unroll")                                                      \
        for (int ks = 0; ks < 2; ++ks)                                         \
            AF[fm][ks] = *(const bf16x8*)&(BASE)[(wm * 64 + fm * 16 + rof) * 64 + \
                                                 (((ks * 4 + kcol) ^ xr) * 8)];

#define LOADBF(BF, BASE)                                                       \
    _Pragma("unroll")                                                          \
    for (int fn = 0; fn < 2; ++fn)                                             \
        _Pragma("unroll")                                                      \
        for (int ks = 0; ks < 2; ++ks)                                         \
            BF[fn][ks] = *(const bf16x8*)&(BASE)[(wn * 32 + fn * 16 + rof) * 64 + \
                                                 (((ks * 4 + kcol) ^ xr) * 8)];

#define MFMA16(AF, BF, RO, CO)                                                 \
    __builtin_amdgcn_s_setprio(1);                                             \
    _Pragma("unroll")                                                          \
    for (int ks = 0; ks < 2; ++ks)                                             \
        _Pragma("unroll")                                                      \
        for (int fm = 0; fm < 4; ++fm)                                         \
            _Pragma("unroll")                                                  \
            for (int fn = 0; fn < 2; ++fn)                                     \
                acc[(RO) + fm][(CO) + fn] =                                    \
                    __builtin_amdgcn_mfma_f32_16x16x32_bf16(                   \
                        AF[fm][ks], BF[fn][ks], acc[(RO) + fm][(CO) + fn], 0, 0, 0); \
    __builtin_amdgcn_s_setprio(0);

#define SBAR  __builtin_amdgcn_s_barrier()
#define SCHED __builtin_amdgcn_sched_barrier(0)

__global__ __launch_bounds__(512, 2) void gemm_kan(
    const unsigned short* __restrict__ A,
    const unsigned short* __restrict__ W,
    float* __restrict__ C, float* __restrict__ Part,
    int kspl, int ktper) {
    __shared__ unsigned short As[2 * 2 * 8192];   // [buf][half][128*64] = 64KB
    __shared__ unsigned short Bs[2 * 2 * 8192];   // 64KB (128KB total)

    const int tid  = threadIdx.x;
    const int wave = tid >> 6;
    const int lane = tid & 63;
    const int per = 16 * kspl;                   // blocks per n-tile
    const int n0  = (blockIdx.x / per) * BN;
    const int r   = blockIdx.x % per;
    const int ksp = r % kspl;
    const int m0  = (r / kspl) * BM;
    const int wm = wave >> 2;                    // 0..1
    const int wn = wave & 3;                     // 0..3

    // staging: linear LDS dest (lane*16B); global source col pre-swizzled so
    // LDS[row][c'] holds global col c' ^ ((row&7)<<4)  (T2, rule #21)
    const int srow = lane >> 3;
    const int scol = 8 * ((lane & 7) ^ (lane >> 3));
    const int kbase = ksp * ktper * BK;

    f32x4 acc[8][4];
#pragma unroll
    for (int a = 0; a < 8; ++a)
#pragma unroll
        for (int b = 0; b < 4; ++b) acc[a][b] = (f32x4){0.f, 0.f, 0.f, 0.f};

    auto stageA = [&](int buf, int h, int kt) {
        const int kk = kbase + kt * BK + scol;
#pragma unroll
        for (int c = 0; c < 2; ++c) {
            const int chunk = wave * 2 + c;      // 0..15 (8-row chunks in half)
            const unsigned short* ga =
                A + (size_t)(m0 + h * 128 + chunk * 8 + srow) * KD + kk;
            __builtin_amdgcn_global_load_lds(
                (const __attribute__((address_space(1))) unsigned int*)ga,
                (__attribute__((address_space(3))) unsigned int*)
                    &As[buf * 16384 + h * 8192 + chunk * 512], 16, 0, 0);
        }
    };
    auto stageB = [&](int buf, int h, int kt) {
        const int kk = kbase + kt * BK + scol;
#pragma unroll
        for (int c = 0; c < 2; ++c) {
            const int chunk = wave * 2 + c;
            const unsigned short* gb =
                W + (size_t)(n0 + h * 128 + chunk * 8 + srow) * KD + kk;
            __builtin_amdgcn_global_load_lds(
                (const __attribute__((address_space(1))) unsigned int*)gb,
                (__attribute__((address_space(3))) unsigned int*)
                    &Bs[buf * 16384 + h * 8192 + chunk * 512], 16, 0, 0);
        }
    };

    // prologue: tile 0 in first-need order Ah0,Bh0,Bh1,Ah1; retire the first
    // two halves (Ah0,Bh0) and publish; Bh1,Ah1 stay in flight (retired at
    // the ph1/ph2 closes of t=0, ages match steady state).
    stageA(0, 0, 0); stageB(0, 0, 0); stageB(0, 1, 0); stageA(0, 1, 0);
    asm volatile("s_waitcnt vmcnt(4)" ::: "memory");
    SBAR;
    SCHED;

    const int rof  = lane & 15;
    const int xr   = lane & 7;
    const int kcol = lane >> 4;

    bf16x8 af[4][2], b0[2][2], b1[2][2];

    for (int t = 0; t < ktper; ++t) {
        const int cur = t & 1;
        const int nxt = cur ^ 1;
        const bool pf = (t + 1 < ktper);
        const unsigned short* Ab = &As[cur * 16384];
        const unsigned short* Bb = &Bs[cur * 16384];

        // ---- ph1: quadrant (H0,F0); 12 ds_reads; stage Ah0(t+1).
        // MFMA paced by compiler-inserted fine-grained lgkmcnt (no drain).
        // close-wait vmcnt(4) retires Bh1(t) (staged ph3(t-1), age 2).
        LOADAF(af, Ab);
        LOADBF(b0, Bb);
        if (pf) stageA(nxt, 0, t + 1);
        SBAR;
        MFMA16(af, b0, 0, 0);
        if (pf) { asm volatile("s_waitcnt vmcnt(4)" ::: "memory"); }
        else    { asm volatile("s_waitcnt vmcnt(2)" ::: "memory"); }
        SBAR;
        SCHED;   // ph2's reads must not hoist above this publication point

        // ---- ph2: (H0,F1); 4 ds_reads (Bh1(t), published at ph1-close);
        // stage Bh0(t+1). close-wait vmcnt(4) retires Ah1(t) (age 2).
        LOADBF(b1, Bb + 8192);
        if (pf) stageB(nxt, 0, t + 1);
        SBAR;
        MFMA16(af, b1, 0, 2);
        if (pf) { asm volatile("s_waitcnt vmcnt(4)" ::: "memory"); }
        else    { asm volatile("s_waitcnt vmcnt(0)" ::: "memory"); }
        SBAR;
        SCHED;   // ph3's reads must not hoist above this publication point

        // ---- ph3: (H1,F1); 8 ds_reads (Ah1(t), published at ph2-close);
        // stage Bh1(t+1). No close-wait needed (ph4 reads no LDS).
        LOADAF(af, Ab + 8192);
        if (pf) stageB(nxt, 1, t + 1);
        SBAR;
        MFMA16(af, b1, 4, 2);
        SBAR;
        SCHED;

        // ---- ph4: (H1,F0); zero ds_reads; stage Ah1(t+1). close-wait
        // vmcnt(4) retires Ah0(t+1),Bh0(t+1) (ages 3,2) for next ph1.
        if (pf) stageA(nxt, 1, t + 1);
        SBAR;
        MFMA16(af, b0, 4, 0);
        if (pf) { asm volatile("s_waitcnt vmcnt(4)" ::: "memory"); }
        SBAR;
        SCHED;   // next ph1's reads must not hoist above this point
    }

    // epilogue: C/D layout col=lane&15, row=(lane>>4)*4+reg
    float* Cp = (ksp == 0) ? C : (Part + (size_t)(ksp - 1) * BATCH * DOUT);
    const int crow = (lane >> 4) * 4;
    const int ccol = lane & 15;
#pragma unroll
    for (int H = 0; H < 2; ++H)
#pragma unroll
        for (int fm = 0; fm < 4; ++fm)
#pragma unroll
            for (int F = 0; F < 2; ++F)
#pragma unroll
                for (int fn = 0; fn < 2; ++fn) {
                    const int row = m0 + H * 128 + wm * 64 + fm * 16 + crow;
                    const int col = n0 + F * 128 + wn * 32 + fn * 16 + ccol;
#pragma unroll
                    for (int rr = 0; rr < 4; ++rr)
                        Cp[(size_t)(row + rr) * DOUT + col] =
                            acc[H * 4 + fm][F * 2 + fn][rr];
                }
}

// ---------------------------------------------------------------------------
// X += sum of np partial slices, float4 vectorized (final layer only)
// ---------------------------------------------------------------------------
__global__ __launch_bounds__(256) void reduce_add(
    const float* __restrict__ P, float* __restrict__ X, int np) {
    const size_t i = ((size_t)blockIdx.x * 256 + threadIdx.x) * 4;
    f32x4 a = *(const f32x4*)(X + i);
    for (int p = 0; p < np; ++p)
        a = a + *(const f32x4*)(P + (size_t)p * BATCH * DOUT + i);
    *(f32x4*)(X + i) = a;
}

// ---------------------------------------------------------------------------
extern "C" void kernel_launch(void* const* d_in, const int* in_sizes, int n_in,
                              void* d_out, int out_size, void* d_ws, size_t ws_size,
                              hipStream_t stream) {
    const float* x        = (const float*)d_in[0];
    const float* base_w   = (const float*)d_in[1];
    const float* spline_w = (const float*)d_in[2];
    const float* scaler   = (const float*)d_in[3];
    const float* grid     = (const float*)d_in[4];
    float* out = (float*)d_out;

    char* ws = (char*)d_ws;
    unsigned short* Abf = (unsigned short*)ws;                       // 100,663,296 B
    unsigned short* Wbf = (unsigned short*)(ws + 100663296);         //  25,165,824 B
    float* xtmp = (float*)(ws + 100663296 + 25165824);               //  16,777,216 B
    float* Part = (float*)(ws + 100663296 + 25165824 + 16777216);    // up to 3x16.8MB

    // kspl=4 needs 3 partial buffers; fall back if scratch is short.
    const size_t base_need = 100663296u + 25165824u + 16777216u;
    const int kspl = (ws_size >= base_need + 3u * 16777216u) ? 4 : 2;
    const int ktper = (KD / BK) / kspl;

    for (int layer = 0; layer < 2; ++layer) {
        const float* xin = (layer == 0) ? x : xtmp;
        float* xout      = (layer == 0) ? xtmp : out;
        build_W<<<4096, 256, 0, stream>>>(base_w + (size_t)layer * DOUT * DIN,
                                          spline_w + (size_t)layer * DOUT * DIN * NC,
                                          scaler + (size_t)layer * DOUT * DIN, Wbf);
        // layer 1's build_A fuses the layer-0 split-K reduce (np = kspl-1)
        build_A<<<16384, 256, 0, stream>>>(xin, Part, (layer == 0) ? 0 : kspl - 1,
                                           grid, Abf);
        gemm_kan<<<64 * kspl, 512, 0, stream>>>(Abf, Wbf, xout, Part, kspl, ktper);
    }
    reduce_add<<<BATCH * DOUT / 1024, 256, 0, stream>>>(Part, out, kspl - 1);
}

// Round 16
// 282.884 us; speedup vs baseline: 1.0981x; 1.0447x over previous
//
#include <hip/hip_runtime.h>
#include <stdint.h>

#define BATCH 4096
#define DIN 1024
#define DOUT 1024
#define NC 11          // GRID_SIZE + SPLINE_ORDER
#define KD 12288       // DIN * (1 + NC)
#define NKNOTS 15      // GRID_SIZE + 2*SPLINE_ORDER + 1

typedef __bf16 bf16x8 __attribute__((ext_vector_type(8)));
typedef float f32x4 __attribute__((ext_vector_type(4)));

__device__ __forceinline__ unsigned short f2bf(float f) {
    unsigned int u = __float_as_uint(f);
    unsigned int r = (u + 0x7FFFu + ((u >> 16) & 1u)) >> 16;
    return (unsigned short)r;
}

// ---------------------------------------------------------------------------
// Build A[b,:] = [ silu(u) | bsplines(silu(u)) ] in bf16, where
// u = x[b,:] (+ sum of np split-K partial slices — fuses the previous layer's
// split-K reduce into this pass).
// ---------------------------------------------------------------------------
__global__ __launch_bounds__(256) void build_A(
    const float* __restrict__ x, const float* __restrict__ P, int np,
    const float* __restrict__ grid, unsigned short* __restrict__ A) {
    __shared__ __align__(16) unsigned short lbs[256 * NC];
    const int tid = threadIdx.x;
    const int b  = blockIdx.x >> 2;
    const int i0 = (blockIdx.x & 3) * 256;
    const int i  = i0 + tid;

    float g[NKNOTS];
#pragma unroll
    for (int j = 0; j < NKNOTS; ++j) g[j] = grid[j];

    float xv = x[(size_t)b * DIN + i];
    for (int p = 0; p < np; ++p)
        xv += P[(size_t)p * BATCH * DIN + (size_t)b * DIN + i];
    const float s = xv / (1.f + __expf(-xv));   // silu

    float bs[14];
#pragma unroll
    for (int c = 0; c < 14; ++c) bs[c] = (s >= g[c] && s < g[c + 1]) ? 1.f : 0.f;
#pragma unroll
    for (int k = 1; k <= 3; ++k) {
        const float inv = (k == 1) ? 4.f : (k == 2) ? 2.f : (4.f / 3.f);
#pragma unroll
        for (int c = 0; c < 14 - k; ++c) {
            float left  = (s - g[c]) * inv;
            float right = (g[c + k + 1] - s) * inv;
            bs[c] = left * bs[c] + right * bs[c + 1];
        }
    }

    A[(size_t)b * KD + i] = f2bf(s);
#pragma unroll
    for (int c = 0; c < NC; ++c) lbs[tid * NC + c] = f2bf(bs[c]);
    __syncthreads();

    const uint4* src = (const uint4*)lbs;
    uint4* dst = (uint4*)(A + (size_t)b * KD + DIN + (size_t)i0 * NC);
    for (int j = tid; j < 352; j += 256) dst[j] = src[j];
}

// ---------------------------------------------------------------------------
// Build W[o, :] = [ base_w[o,:] | spline_w[o,:,:]*scaler[o,:] ] in bf16
// ---------------------------------------------------------------------------
__global__ __launch_bounds__(256) void build_W(
    const float* __restrict__ base_w, const float* __restrict__ spline_w,
    const float* __restrict__ scaler, unsigned short* __restrict__ W) {
    __shared__ __align__(16) unsigned short lw[256 * NC];
    const int tid = threadIdx.x;
    const int o  = blockIdx.x >> 2;
    const int i0 = (blockIdx.x & 3) * 256;
    const int i  = i0 + tid;
    const size_t oi = (size_t)o * DIN + i;

    const float sc = scaler[oi];
    W[(size_t)o * KD + i] = f2bf(base_w[oi]);
    const float* sw = spline_w + oi * NC;
#pragma unroll
    for (int c = 0; c < NC; ++c) lw[tid * NC + c] = f2bf(sw[c] * sc);
    __syncthreads();

    const uint4* src = (const uint4*)lw;
    uint4* dst = (uint4*)(W + (size_t)o * KD + DIN + (size_t)i0 * NC);
    for (int j = tid; j < 352; j += 256) dst[j] = src[j];
}

// ---------------------------------------------------------------------------
// GEMM (split-K): C = A[4096,12288] @ W[1024,12288]^T, f32 out.
// R16 = R15 champion MINUS all non-publishing barriers: 3 barriers/K-tile,
// each preceded by its publication vmcnt. Phases:
//   P1: read a0,b0 (12 ds); stage Ah0'; MFMA q1;           W1=vmcnt(4); BAR1
//   P2: read b1     (4 ds); stage Bh0'; MFMA q2;           W2=vmcnt(4); BAR2
//   P3: read a1     (8 ds); stage Bh1'; MFMA q3;
//                           stage Ah1'; MFMA q4;           W3=vmcnt(4); BAR3
// Ledger (steady state): W1 retires Bh1(t) [read P2], W2 retires Ah1(t)
// [read P3], W3 retires Ah0',Bh0' [read P1(t+1)] — all >=2 phases old.
// Tail (last tile, no stages): W1=vmcnt(2), W2=vmcnt(0), W3 skipped.
// Staging stays spread 1-2 halves/phase in first-need order (R9/R10 showed
// bunching costs ~10%). ds_reads are C++ loads -> compiler emits fine-grained
// lgkmcnt per MFMA; longer inter-barrier regions let wave skew develop so
// one wave's MFMA drain covers another's ds_reads. T2 XOR-swizzle,
// n-grouped block map, setprio on MFMA clusters.
// ---------------------------------------------------------------------------
#define BM 256
#define BN 256
#define BK 64

#define LOADAF(AF, BASE)                                                       \
    _Pragma("unroll")                                                          \
    for (int fm = 0; fm < 4; ++fm)                                             \
        _Pragma("unroll")                                                      \
        for (int ks = 0; ks < 2; ++ks)                                         \
            AF[fm][ks] = *(const bf16x8*)&(BASE)[(wm * 64 + fm * 16 + rof) * 64 + \
                                                 (((ks * 4 + kcol) ^ xr) * 8)];

#define LOADBF(BF, BASE)                                                       \
    _Pragma("unroll")                                                          \
    for (int fn = 0; fn < 2; ++fn)                                             \
        _Pragma("unroll")                                                      \
        for (int ks = 0; ks < 2; ++ks)                                         \
            BF[fn][ks] = *(const bf16x8*)&(BASE)[(wn * 32 + fn * 16 + rof) * 64 + \
                                                 (((ks * 4 + kcol) ^ xr) * 8)];

#define MFMA16(AF, BF, RO, CO)                                                 \
    __builtin_amdgcn_s_setprio(1);                                             \
    _Pragma("unroll")                                                          \
    for (int ks = 0; ks < 2; ++ks)                                             \
        _Pragma("unroll")                                                      \
        for (int fm = 0; fm < 4; ++fm)                                         \
            _Pragma("unroll")                                                  \
            for (int fn = 0; fn < 2; ++fn)                                     \
                acc[(RO) + fm][(CO) + fn] =                                    \
                    __builtin_amdgcn_mfma_f32_16x16x32_bf16(                   \
                        AF[fm][ks], BF[fn][ks], acc[(RO) + fm][(CO) + fn], 0, 0, 0); \
    __builtin_amdgcn_s_setprio(0);

#define SBAR  __builtin_amdgcn_s_barrier()
#define SCHED __builtin_amdgcn_sched_barrier(0)

__global__ __launch_bounds__(512, 2) void gemm_kan(
    const unsigned short* __restrict__ A,
    const unsigned short* __restrict__ W,
    float* __restrict__ C, float* __restrict__ Part,
    int kspl, int ktper) {
    __shared__ unsigned short As[2 * 2 * 8192];   // [buf][half][128*64] = 64KB
    __shared__ unsigned short Bs[2 * 2 * 8192];   // 64KB (128KB total)

    const int tid  = threadIdx.x;
    const int wave = tid >> 6;
    const int lane = tid & 63;
    const int per = 16 * kspl;                   // blocks per n-tile
    const int n0  = (blockIdx.x / per) * BN;
    const int r   = blockIdx.x % per;
    const int ksp = r % kspl;
    const int m0  = (r / kspl) * BM;
    const int wm = wave >> 2;                    // 0..1
    const int wn = wave & 3;                     // 0..3

    // staging: linear LDS dest (lane*16B); global source col pre-swizzled so
    // LDS[row][c'] holds global col c' ^ ((row&7)<<4)  (T2, rule #21)
    const int srow = lane >> 3;
    const int scol = 8 * ((lane & 7) ^ (lane >> 3));
    const int kbase = ksp * ktper * BK;

    f32x4 acc[8][4];
#pragma unroll
    for (int a = 0; a < 8; ++a)
#pragma unroll
        for (int b = 0; b < 4; ++b) acc[a][b] = (f32x4){0.f, 0.f, 0.f, 0.f};

    auto stageA = [&](int buf, int h, int kt) {
        const int kk = kbase + kt * BK + scol;
#pragma unroll
        for (int c = 0; c < 2; ++c) {
            const int chunk = wave * 2 + c;      // 0..15 (8-row chunks in half)
            const unsigned short* ga =
                A + (size_t)(m0 + h * 128 + chunk * 8 + srow) * KD + kk;
            __builtin_amdgcn_global_load_lds(
                (const __attribute__((address_space(1))) unsigned int*)ga,
                (__attribute__((address_space(3))) unsigned int*)
                    &As[buf * 16384 + h * 8192 + chunk * 512], 16, 0, 0);
        }
    };
    auto stageB = [&](int buf, int h, int kt) {
        const int kk = kbase + kt * BK + scol;
#pragma unroll
        for (int c = 0; c < 2; ++c) {
            const int chunk = wave * 2 + c;
            const unsigned short* gb =
                W + (size_t)(n0 + h * 128 + chunk * 8 + srow) * KD + kk;
            __builtin_amdgcn_global_load_lds(
                (const __attribute__((address_space(1))) unsigned int*)gb,
                (__attribute__((address_space(3))) unsigned int*)
                    &Bs[buf * 16384 + h * 8192 + chunk * 512], 16, 0, 0);
        }
    };

    // prologue: tile 0 in first-need order Ah0,Bh0,Bh1,Ah1; retire Ah0,Bh0
    // (both read by P1) and publish; Bh1,Ah1 stay in flight.
    stageA(0, 0, 0); stageB(0, 0, 0); stageB(0, 1, 0); stageA(0, 1, 0);
    asm volatile("s_waitcnt vmcnt(4)" ::: "memory");
    SBAR;
    SCHED;

    const int rof  = lane & 15;
    const int xr   = lane & 7;
    const int kcol = lane >> 4;

    bf16x8 af[4][2], b0[2][2], b1[2][2];

    for (int t = 0; t < ktper; ++t) {
        const int cur = t & 1;
        const int nxt = cur ^ 1;
        const bool pf = (t + 1 < ktper);
        const unsigned short* Ab = &As[cur * 16384];
        const unsigned short* Bb = &Bs[cur * 16384];

        // ---- P1: (H0,F0). 12 ds_reads; stage Ah0(t+1); MFMA q1 paced by
        // compiler lgkm. W1 retires Bh1(t) (staged P3(t-1), age 2 phases).
        LOADAF(af, Ab);
        LOADBF(b0, Bb);
        if (pf) stageA(nxt, 0, t + 1);
        MFMA16(af, b0, 0, 0);
        SCHED;
        if (pf) { asm volatile("s_waitcnt vmcnt(4)" ::: "memory"); }
        else    { asm volatile("s_waitcnt vmcnt(2)" ::: "memory"); }
        SBAR;
        SCHED;   // P2's reads must not hoist above this publication point

        // ---- P2: (H0,F1). 4 ds_reads (Bh1(t)); stage Bh0(t+1); MFMA q2.
        // W2 retires Ah1(t) (staged P3(t-1), age 2 phases).
        LOADBF(b1, Bb + 8192);
        if (pf) stageB(nxt, 0, t + 1);
        MFMA16(af, b1, 0, 2);
        SCHED;
        if (pf) { asm volatile("s_waitcnt vmcnt(4)" ::: "memory"); }
        else    { asm volatile("s_waitcnt vmcnt(0)" ::: "memory"); }
        SBAR;
        SCHED;   // P3's reads must not hoist above this publication point

        // ---- P3: (H1,*). 8 ds_reads (Ah1(t)); stage Bh1(t+1); MFMA q3;
        // stage Ah1(t+1); MFMA q4 (register-fed). W3 retires Ah0(t+1),
        // Bh0(t+1) (ages 3,2 phases) for P1(t+1)'s reads.
        LOADAF(af, Ab + 8192);
        if (pf) stageB(nxt, 1, t + 1);
        MFMA16(af, b1, 4, 2);
        if (pf) stageA(nxt, 1, t + 1);
        MFMA16(af, b0, 4, 0);
        SCHED;
        if (pf) { asm volatile("s_waitcnt vmcnt(4)" ::: "memory"); }
        SBAR;
        SCHED;   // next P1's reads must not hoist above this point
    }

    // epilogue: C/D layout col=lane&15, row=(lane>>4)*4+reg
    float* Cp = (ksp == 0) ? C : (Part + (size_t)(ksp - 1) * BATCH * DOUT);
    const int crow = (lane >> 4) * 4;
    const int ccol = lane & 15;
#pragma unroll
    for (int H = 0; H < 2; ++H)
#pragma unroll
        for (int fm = 0; fm < 4; ++fm)
#pragma unroll
            for (int F = 0; F < 2; ++F)
#pragma unroll
                for (int fn = 0; fn < 2; ++fn) {
                    const int row = m0 + H * 128 + wm * 64 + fm * 16 + crow;
                    const int col = n0 + F * 128 + wn * 32 + fn * 16 + ccol;
#pragma unroll
                    for (int rr = 0; rr < 4; ++rr)
                        Cp[(size_t)(row + rr) * DOUT + col] =
                            acc[H * 4 + fm][F * 2 + fn][rr];
                }
}

// ---------------------------------------------------------------------------
// X += sum of np partial slices, float4 vectorized (final layer only)
// ---------------------------------------------------------------------------
__global__ __launch_bounds__(256) void reduce_add(
    const float* __restrict__ P, float* __restrict__ X, int np) {
    const size_t i = ((size_t)blockIdx.x * 256 + threadIdx.x) * 4;
    f32x4 a = *(const f32x4*)(X + i);
    for (int p = 0; p < np; ++p)
        a = a + *(const f32x4*)(P + (size_t)p * BATCH * DOUT + i);
    *(f32x4*)(X + i) = a;
}

// ---------------------------------------------------------------------------
extern "C" void kernel_launch(void* const* d_in, const int* in_sizes, int n_in,
                              void* d_out, int out_size, void* d_ws, size_t ws_size,
                              hipStream_t stream) {
    const float* x        = (const float*)d_in[0];
    const float* base_w   = (const float*)d_in[1];
    const float* spline_w = (const float*)d_in[2];
    const float* scaler   = (const float*)d_in[3];
    const float* grid     = (const float*)d_in[4];
    float* out = (float*)d_out;

    char* ws = (char*)d_ws;
    unsigned short* Abf = (unsigned short*)ws;                       // 100,663,296 B
    unsigned short* Wbf = (unsigned short*)(ws + 100663296);         //  25,165,824 B
    float* xtmp = (float*)(ws + 100663296 + 25165824);               //  16,777,216 B
    float* Part = (float*)(ws + 100663296 + 25165824 + 16777216);    // up to 3x16.8MB

    // kspl=4 needs 3 partial buffers; fall back if scratch is short.
    const size_t base_need = 100663296u + 25165824u + 16777216u;
    const int kspl = (ws_size >= base_need + 3u * 16777216u) ? 4 : 2;
    const int ktper = (KD / BK) / kspl;

    for (int layer = 0; layer < 2; ++layer) {
        const float* xin = (layer == 0) ? x : xtmp;
        float* xout      = (layer == 0) ? xtmp : out;
        build_W<<<4096, 256, 0, stream>>>(base_w + (size_t)layer * DOUT * DIN,
                                          spline_w + (size_t)layer * DOUT * DIN * NC,
                                          scaler + (size_t)layer * DOUT * DIN, Wbf);
        // layer 1's build_A fuses the layer-0 split-K reduce (np = kspl-1)
        build_A<<<16384, 256, 0, stream>>>(xin, Part, (layer == 0) ? 0 : kspl - 1,
                                           grid, Abf);
        gemm_kan<<<64 * kspl, 512, 0, stream>>>(Abf, Wbf, xout, Part, kspl, ktper);
    }
    reduce_add<<<BATCH * DOUT / 1024, 256, 0, stream>>>(Part, out, kspl - 1);
}

// Round 17
// 278.913 us; speedup vs baseline: 1.1137x; 1.0142x over previous
//
#include <hip/hip_runtime.h>
#include <stdint.h>

#define BATCH 4096
#define DIN 1024
#define DOUT 1024
#define NC 11          // GRID_SIZE + SPLINE_ORDER
#define KD 12288       // DIN * (1 + NC)
#define NKNOTS 15      // GRID_SIZE + 2*SPLINE_ORDER + 1

typedef __bf16 bf16x8 __attribute__((ext_vector_type(8)));
typedef float f32x4 __attribute__((ext_vector_type(4)));

__device__ __forceinline__ unsigned short f2bf(float f) {
    unsigned int u = __float_as_uint(f);
    unsigned int r = (u + 0x7FFFu + ((u >> 16) & 1u)) >> 16;
    return (unsigned short)r;
}

// ---------------------------------------------------------------------------
// Build A[b,:] = [ silu(u) | bsplines(silu(u)) ] in bf16, where
// u = x[b,:] (+ sum of np split-K partial slices — fuses the previous layer's
// split-K reduce into this pass).
// ---------------------------------------------------------------------------
__global__ __launch_bounds__(256) void build_A(
    const float* __restrict__ x, const float* __restrict__ P, int np,
    const float* __restrict__ grid, unsigned short* __restrict__ A) {
    __shared__ __align__(16) unsigned short lbs[256 * NC];
    const int tid = threadIdx.x;
    const int b  = blockIdx.x >> 2;
    const int i0 = (blockIdx.x & 3) * 256;
    const int i  = i0 + tid;

    float g[NKNOTS];
#pragma unroll
    for (int j = 0; j < NKNOTS; ++j) g[j] = grid[j];

    float xv = x[(size_t)b * DIN + i];
    for (int p = 0; p < np; ++p)
        xv += P[(size_t)p * BATCH * DIN + (size_t)b * DIN + i];
    const float s = xv / (1.f + __expf(-xv));   // silu

    float bs[14];
#pragma unroll
    for (int c = 0; c < 14; ++c) bs[c] = (s >= g[c] && s < g[c + 1]) ? 1.f : 0.f;
#pragma unroll
    for (int k = 1; k <= 3; ++k) {
        const float inv = (k == 1) ? 4.f : (k == 2) ? 2.f : (4.f / 3.f);
#pragma unroll
        for (int c = 0; c < 14 - k; ++c) {
            float left  = (s - g[c]) * inv;
            float right = (g[c + k + 1] - s) * inv;
            bs[c] = left * bs[c] + right * bs[c + 1];
        }
    }

    A[(size_t)b * KD + i] = f2bf(s);
#pragma unroll
    for (int c = 0; c < NC; ++c) lbs[tid * NC + c] = f2bf(bs[c]);
    __syncthreads();

    const uint4* src = (const uint4*)lbs;
    uint4* dst = (uint4*)(A + (size_t)b * KD + DIN + (size_t)i0 * NC);
    for (int j = tid; j < 352; j += 256) dst[j] = src[j];
}

// ---------------------------------------------------------------------------
// Build W[o, :] = [ base_w[o,:] | spline_w[o,:,:]*scaler[o,:] ] in bf16
// ---------------------------------------------------------------------------
__global__ __launch_bounds__(256) void build_W(
    const float* __restrict__ base_w, const float* __restrict__ spline_w,
    const float* __restrict__ scaler, unsigned short* __restrict__ W) {
    __shared__ __align__(16) unsigned short lw[256 * NC];
    const int tid = threadIdx.x;
    const int o  = blockIdx.x >> 2;
    const int i0 = (blockIdx.x & 3) * 256;
    const int i  = i0 + tid;
    const size_t oi = (size_t)o * DIN + i;

    const float sc = scaler[oi];
    W[(size_t)o * KD + i] = f2bf(base_w[oi]);
    const float* sw = spline_w + oi * NC;
#pragma unroll
    for (int c = 0; c < NC; ++c) lw[tid * NC + c] = f2bf(sw[c] * sc);
    __syncthreads();

    const uint4* src = (const uint4*)lw;
    uint4* dst = (uint4*)(W + (size_t)o * KD + DIN + (size_t)i0 * NC);
    for (int j = tid; j < 352; j += 256) dst[j] = src[j];
}

// ---------------------------------------------------------------------------
// GEMM (split-K): C = A[4096,12288] @ W[1024,12288]^T, f32 out.
// R17 = R16 minus one more re-sync: 2 barriers/K-tile.
//   PA: read a0,b0,b1 (16 ds); stage Ah0',Bh0'; MFMA q1,q2;
//       W_A=vmcnt(4) [retires Ah1(t), age 2 phases;
//       outstanding: Ah1(t),Ah0',Bh0' = 6]; BAR_A
//   PB: read a1 (8 ds); stage Bh1'; MFMA q3; stage Ah1'; MFMA q4;
//       W_B=vmcnt(2) [retires Ah0',Bh0',Bh1' for PA(t+1); keeps Ah1'];
//       BAR_B
// Tail: W_A=vmcnt(0); W_B skipped. Every staged region >=2 barriers past its
// last reader; every ds_read follows its half's publication barrier.
// q2's b1-reads issue while q1's MFMAs drain (no barrier between — compiler
// paces with fine-grained lgkmcnt on C++ loads). Staging spread 2 halves per
// phase (bunching costs ~10%, R9/R10). T2 XOR-swizzle, n-grouped block map,
// setprio on MFMA clusters.
// ---------------------------------------------------------------------------
#define BM 256
#define BN 256
#define BK 64

#define LOADAF(AF, BASE)                                                       \
    _Pragma("unroll")                                                          \
    for (int fm = 0; fm < 4; ++fm)                                             \
        _Pragma("unroll")                                                      \
        for (int ks = 0; ks < 2; ++ks)                                         \
            AF[fm][ks] = *(const bf16x8*)&(BASE)[(wm * 64 + fm * 16 + rof) * 64 + \
                                                 (((ks * 4 + kcol) ^ xr) * 8)];

#define LOADBF(BF, BASE)                                                       \
    _Pragma("unroll")                                                          \
    for (int fn = 0; fn < 2; ++fn)                                             \
        _Pragma("unroll")                                                      \
        for (int ks = 0; ks < 2; ++ks)                                         \
            BF[fn][ks] = *(const bf16x8*)&(BASE)[(wn * 32 + fn * 16 + rof) * 64 + \
                                                 (((ks * 4 + kcol) ^ xr) * 8)];

#define MFMA16(AF, BF, RO, CO)                                                 \
    __builtin_amdgcn_s_setprio(1);                                             \
    _Pragma("unroll")                                                          \
    for (int ks = 0; ks < 2; ++ks)                                             \
        _Pragma("unroll")                                                      \
        for (int fm = 0; fm < 4; ++fm)                                         \
            _Pragma("unroll")                                                  \
            for (int fn = 0; fn < 2; ++fn)                                     \
                acc[(RO) + fm][(CO) + fn] =                                    \
                    __builtin_amdgcn_mfma_f32_16x16x32_bf16(                   \
                        AF[fm][ks], BF[fn][ks], acc[(RO) + fm][(CO) + fn], 0, 0, 0); \
    __builtin_amdgcn_s_setprio(0);

#define SBAR  __builtin_amdgcn_s_barrier()
#define SCHED __builtin_amdgcn_sched_barrier(0)

__global__ __launch_bounds__(512, 2) void gemm_kan(
    const unsigned short* __restrict__ A,
    const unsigned short* __restrict__ W,
    float* __restrict__ C, float* __restrict__ Part,
    int kspl, int ktper) {
    __shared__ unsigned short As[2 * 2 * 8192];   // [buf][half][128*64] = 64KB
    __shared__ unsigned short Bs[2 * 2 * 8192];   // 64KB (128KB total)

    const int tid  = threadIdx.x;
    const int wave = tid >> 6;
    const int lane = tid & 63;
    const int per = 16 * kspl;                   // blocks per n-tile
    const int n0  = (blockIdx.x / per) * BN;
    const int r   = blockIdx.x % per;
    const int ksp = r % kspl;
    const int m0  = (r / kspl) * BM;
    const int wm = wave >> 2;                    // 0..1
    const int wn = wave & 3;                     // 0..3

    // staging: linear LDS dest (lane*16B); global source col pre-swizzled so
    // LDS[row][c'] holds global col c' ^ ((row&7)<<4)  (T2, rule #21)
    const int srow = lane >> 3;
    const int scol = 8 * ((lane & 7) ^ (lane >> 3));
    const int kbase = ksp * ktper * BK;

    f32x4 acc[8][4];
#pragma unroll
    for (int a = 0; a < 8; ++a)
#pragma unroll
        for (int b = 0; b < 4; ++b) acc[a][b] = (f32x4){0.f, 0.f, 0.f, 0.f};

    auto stageA = [&](int buf, int h, int kt) {
        const int kk = kbase + kt * BK + scol;
#pragma unroll
        for (int c = 0; c < 2; ++c) {
            const int chunk = wave * 2 + c;      // 0..15 (8-row chunks in half)
            const unsigned short* ga =
                A + (size_t)(m0 + h * 128 + chunk * 8 + srow) * KD + kk;
            __builtin_amdgcn_global_load_lds(
                (const __attribute__((address_space(1))) unsigned int*)ga,
                (__attribute__((address_space(3))) unsigned int*)
                    &As[buf * 16384 + h * 8192 + chunk * 512], 16, 0, 0);
        }
    };
    auto stageB = [&](int buf, int h, int kt) {
        const int kk = kbase + kt * BK + scol;
#pragma unroll
        for (int c = 0; c < 2; ++c) {
            const int chunk = wave * 2 + c;
            const unsigned short* gb =
                W + (size_t)(n0 + h * 128 + chunk * 8 + srow) * KD + kk;
            __builtin_amdgcn_global_load_lds(
                (const __attribute__((address_space(1))) unsigned int*)gb,
                (__attribute__((address_space(3))) unsigned int*)
                    &Bs[buf * 16384 + h * 8192 + chunk * 512], 16, 0, 0);
        }
    };

    // prologue: tile 0 in order Ah0,Bh0,Bh1,Ah1; retire first three halves
    // (PA(0) reads a0,b0,b1); keep Ah1(0) in flight (retired at W_A(0)).
    stageA(0, 0, 0); stageB(0, 0, 0); stageB(0, 1, 0); stageA(0, 1, 0);
    asm volatile("s_waitcnt vmcnt(2)" ::: "memory");
    SBAR;
    SCHED;

    const int rof  = lane & 15;
    const int xr   = lane & 7;
    const int kcol = lane >> 4;

    bf16x8 af[4][2], b0[2][2], b1[2][2];

    for (int t = 0; t < ktper; ++t) {
        const int cur = t & 1;
        const int nxt = cur ^ 1;
        const bool pf = (t + 1 < ktper);
        const unsigned short* Ab = &As[cur * 16384];
        const unsigned short* Bb = &Bs[cur * 16384];

        // ---- PA: (H0, F0+F1). 16 ds_reads; stage Ah0(t+1), Bh0(t+1);
        // MFMA q1,q2 paced by compiler lgkm (b1 reads drain under q1).
        // W_A retires Ah1(t) (staged PB(t-1), age 2 phases).
        LOADAF(af, Ab);
        LOADBF(b0, Bb);
        LOADBF(b1, Bb + 8192);
        if (pf) { stageA(nxt, 0, t + 1); stageB(nxt, 0, t + 1); }
        MFMA16(af, b0, 0, 0);
        MFMA16(af, b1, 0, 2);
        SCHED;
        if (pf) { asm volatile("s_waitcnt vmcnt(4)" ::: "memory"); }
        else    { asm volatile("s_waitcnt vmcnt(0)" ::: "memory"); }
        SBAR;
        SCHED;   // PB's reads must not hoist above this publication point

        // ---- PB: (H1, F1+F0). 8 ds_reads (Ah1(t)); stage Bh1(t+1); q3;
        // stage Ah1(t+1); q4 (register-fed). W_B retires Ah0',Bh0',Bh1'
        // (ages 2,2,1 phases) for PA(t+1); keeps Ah1' in flight.
        LOADAF(af, Ab + 8192);
        if (pf) stageB(nxt, 1, t + 1);
        MFMA16(af, b1, 4, 2);
        if (pf) stageA(nxt, 1, t + 1);
        MFMA16(af, b0, 4, 0);
        SCHED;
        if (pf) {
            asm volatile("s_waitcnt vmcnt(2)" ::: "memory");
            SBAR;
            SCHED;   // next PA's reads must not hoist above this point
        }
    }

    // epilogue: C/D layout col=lane&15, row=(lane>>4)*4+reg
    float* Cp = (ksp == 0) ? C : (Part + (size_t)(ksp - 1) * BATCH * DOUT);
    const int crow = (lane >> 4) * 4;
    const int ccol = lane & 15;
#pragma unroll
    for (int H = 0; H < 2; ++H)
#pragma unroll
        for (int fm = 0; fm < 4; ++fm)
#pragma unroll
            for (int F = 0; F < 2; ++F)
#pragma unroll
                for (int fn = 0; fn < 2; ++fn) {
                    const int row = m0 + H * 128 + wm * 64 + fm * 16 + crow;
                    const int col = n0 + F * 128 + wn * 32 + fn * 16 + ccol;
#pragma unroll
                    for (int rr = 0; rr < 4; ++rr)
                        Cp[(size_t)(row + rr) * DOUT + col] =
                            acc[H * 4 + fm][F * 2 + fn][rr];
                }
}

// ---------------------------------------------------------------------------
// X += sum of np partial slices, float4 vectorized (final layer only)
// ---------------------------------------------------------------------------
__global__ __launch_bounds__(256) void reduce_add(
    const float* __restrict__ P, float* __restrict__ X, int np) {
    const size_t i = ((size_t)blockIdx.x * 256 + threadIdx.x) * 4;
    f32x4 a = *(const f32x4*)(X + i);
    for (int p = 0; p < np; ++p)
        a = a + *(const f32x4*)(P + (size_t)p * BATCH * DOUT + i);
    *(f32x4*)(X + i) = a;
}

// ---------------------------------------------------------------------------
extern "C" void kernel_launch(void* const* d_in, const int* in_sizes, int n_in,
                              void* d_out, int out_size, void* d_ws, size_t ws_size,
                              hipStream_t stream) {
    const float* x        = (const float*)d_in[0];
    const float* base_w   = (const float*)d_in[1];
    const float* spline_w = (const float*)d_in[2];
    const float* scaler   = (const float*)d_in[3];
    const float* grid     = (const float*)d_in[4];
    float* out = (float*)d_out;

    char* ws = (char*)d_ws;
    unsigned short* Abf = (unsigned short*)ws;                       // 100,663,296 B
    unsigned short* Wbf = (unsigned short*)(ws + 100663296);         //  25,165,824 B
    float* xtmp = (float*)(ws + 100663296 + 25165824);               //  16,777,216 B
    float* Part = (float*)(ws + 100663296 + 25165824 + 16777216);    // up to 3x16.8MB

    // kspl=4 needs 3 partial buffers; fall back if scratch is short.
    const size_t base_need = 100663296u + 25165824u + 16777216u;
    const int kspl = (ws_size >= base_need + 3u * 16777216u) ? 4 : 2;
    const int ktper = (KD / BK) / kspl;

    for (int layer = 0; layer < 2; ++layer) {
        const float* xin = (layer == 0) ? x : xtmp;
        float* xout      = (layer == 0) ? xtmp : out;
        build_W<<<4096, 256, 0, stream>>>(base_w + (size_t)layer * DOUT * DIN,
                                          spline_w + (size_t)layer * DOUT * DIN * NC,
                                          scaler + (size_t)layer * DOUT * DIN, Wbf);
        // layer 1's build_A fuses the layer-0 split-K reduce (np = kspl-1)
        build_A<<<16384, 256, 0, stream>>>(xin, Part, (layer == 0) ? 0 : kspl - 1,
                                           grid, Abf);
        gemm_kan<<<64 * kspl, 512, 0, stream>>>(Abf, Wbf, xout, Part, kspl, ktper);
    }
    reduce_add<<<BATCH * DOUT / 1024, 256, 0, stream>>>(Part, out, kspl - 1);
}

// Round 19
// 275.587 us; speedup vs baseline: 1.1271x; 1.0121x over previous
//
#include <hip/hip_runtime.h>
#include <stdint.h>

#define BATCH 4096
#define DIN 1024
#define DOUT 1024
#define NC 11          // GRID_SIZE + SPLINE_ORDER
#define KD 12288       // DIN * (1 + NC)
#define NKNOTS 15      // GRID_SIZE + 2*SPLINE_ORDER + 1

typedef __bf16 bf16x8 __attribute__((ext_vector_type(8)));
typedef float f32x4 __attribute__((ext_vector_type(4)));

__device__ __forceinline__ unsigned short f2bf(float f) {
    unsigned int u = __float_as_uint(f);
    unsigned int r = (u + 0x7FFFu + ((u >> 16) & 1u)) >> 16;
    return (unsigned short)r;
}

// ---------------------------------------------------------------------------
// Build A[b,:] = [ silu(u) | bsplines(silu(u)) ] in bf16, where
// u = x[b,:] (+ sum of np split-K partial slices — fuses the previous layer's
// split-K reduce into this pass).
// ---------------------------------------------------------------------------
__global__ __launch_bounds__(256) void build_A(
    const float* __restrict__ x, const float* __restrict__ P, int np,
    const float* __restrict__ grid, unsigned short* __restrict__ A) {
    __shared__ __align__(16) unsigned short lbs[256 * NC];
    const int tid = threadIdx.x;
    const int b  = blockIdx.x >> 2;
    const int i0 = (blockIdx.x & 3) * 256;
    const int i  = i0 + tid;

    float g[NKNOTS];
#pragma unroll
    for (int j = 0; j < NKNOTS; ++j) g[j] = grid[j];

    float xv = x[(size_t)b * DIN + i];
    for (int p = 0; p < np; ++p)
        xv += P[(size_t)p * BATCH * DIN + (size_t)b * DIN + i];
    const float s = xv / (1.f + __expf(-xv));   // silu

    float bs[14];
#pragma unroll
    for (int c = 0; c < 14; ++c) bs[c] = (s >= g[c] && s < g[c + 1]) ? 1.f : 0.f;
#pragma unroll
    for (int k = 1; k <= 3; ++k) {
        const float inv = (k == 1) ? 4.f : (k == 2) ? 2.f : (4.f / 3.f);
#pragma unroll
        for (int c = 0; c < 14 - k; ++c) {
            float left  = (s - g[c]) * inv;
            float right = (g[c + k + 1] - s) * inv;
            bs[c] = left * bs[c] + right * bs[c + 1];
        }
    }

    A[(size_t)b * KD + i] = f2bf(s);
#pragma unroll
    for (int c = 0; c < NC; ++c) lbs[tid * NC + c] = f2bf(bs[c]);
    __syncthreads();

    const uint4* src = (const uint4*)lbs;
    uint4* dst = (uint4*)(A + (size_t)b * KD + DIN + (size_t)i0 * NC);
    for (int j = tid; j < 352; j += 256) dst[j] = src[j];
}

// ---------------------------------------------------------------------------
// Build W[o, :] = [ base_w[o,:] | spline_w[o,:,:]*scaler[o,:] ] in bf16
// ---------------------------------------------------------------------------
__global__ __launch_bounds__(256) void build_W(
    const float* __restrict__ base_w, const float* __restrict__ spline_w,
    const float* __restrict__ scaler, unsigned short* __restrict__ W) {
    __shared__ __align__(16) unsigned short lw[256 * NC];
    const int tid = threadIdx.x;
    const int o  = blockIdx.x >> 2;
    const int i0 = (blockIdx.x & 3) * 256;
    const int i  = i0 + tid;
    const size_t oi = (size_t)o * DIN + i;

    const float sc = scaler[oi];
    W[(size_t)o * KD + i] = f2bf(base_w[oi]);
    const float* sw = spline_w + oi * NC;
#pragma unroll
    for (int c = 0; c < NC; ++c) lw[tid * NC + c] = f2bf(sw[c] * sc);
    __syncthreads();

    const uint4* src = (const uint4*)lw;
    uint4* dst = (uint4*)(W + (size_t)o * KD + DIN + (size_t)i0 * NC);
    for (int j = tid; j < 352; j += 256) dst[j] = src[j];
}

// ---------------------------------------------------------------------------
// GEMM (split-K): C = A[4096,12288] @ W[1024,12288]^T, f32 out.
// R18 = R17 minus the mid barrier: ONE barrier per K-tile (the dbuf limit).
// Region t (between BAR(t) and BAR(t+1)):
//   reads a0,b0,b1 (16 ds); stage Ah0',Bh0'; MFMA q1;
//   stage Bh1'; MFMA q2; read a1 (8 ds); stage Ah1'; MFMA q3; MFMA q4;
//   W=vmcnt(0) [retires all 8 t+1 halves; youngest staged >=2 MFMA clusters
//   (~1200cy) before the wait, oldest ~4000cy -> free]; BAR.
// Safety: BAR(t) orders all waves' tile-(t-1) ds_reads (each retired before
// its consuming MFMA, which precedes BAR(t)) before tile-(t+1) stage-writes
// land in the same buffer. All tile-t reads sit after BAR(t)'s publication.
// Tail tile stages nothing and skips the trailing wait+barrier.
// Staging spread through the region (bunching costs ~10%: R9/R10). ds_reads
// are C++ loads -> compiler paces MFMA with fine-grained lgkmcnt; with no
// mid-region re-sync, wave skew lets one wave's MFMA drain cover another's
// ds_reads. T2 XOR-swizzle, n-grouped block map, setprio on MFMA clusters.
// ---------------------------------------------------------------------------
#define BM 256
#define BN 256
#define BK 64

#define LOADAF(AF, BASE)                                                       \
    _Pragma("unroll")                                                          \
    for (int fm = 0; fm < 4; ++fm)                                             \
        _Pragma("unroll")                                                      \
        for (int ks = 0; ks < 2; ++ks)                                         \
            AF[fm][ks] = *(const bf16x8*)&(BASE)[(wm * 64 + fm * 16 + rof) * 64 + \
                                                 (((ks * 4 + kcol) ^ xr) * 8)];

#define LOADBF(BF, BASE)                                                       \
    _Pragma("unroll")                                                          \
    for (int fn = 0; fn < 2; ++fn)                                             \
        _Pragma("unroll")                                                      \
        for (int ks = 0; ks < 2; ++ks)                                         \
            BF[fn][ks] = *(const bf16x8*)&(BASE)[(wn * 32 + fn * 16 + rof) * 64 + \
                                                 (((ks * 4 + kcol) ^ xr) * 8)];

#define MFMA16(AF, BF, RO, CO)                                                 \
    __builtin_amdgcn_s_setprio(1);                                             \
    _Pragma("unroll")                                                          \
    for (int ks = 0; ks < 2; ++ks)                                             \
        _Pragma("unroll")                                                      \
        for (int fm = 0; fm < 4; ++fm)                                         \
            _Pragma("unroll")                                                  \
            for (int fn = 0; fn < 2; ++fn)                                     \
                acc[(RO) + fm][(CO) + fn] =                                    \
                    __builtin_amdgcn_mfma_f32_16x16x32_bf16(                   \
                        AF[fm][ks], BF[fn][ks], acc[(RO) + fm][(CO) + fn], 0, 0, 0); \
    __builtin_amdgcn_s_setprio(0);

#define SBAR  __builtin_amdgcn_s_barrier()
#define SCHED __builtin_amdgcn_sched_barrier(0)

__global__ __launch_bounds__(512, 2) void gemm_kan(
    const unsigned short* __restrict__ A,
    const unsigned short* __restrict__ W,
    float* __restrict__ C, float* __restrict__ Part,
    int kspl, int ktper) {
    __shared__ unsigned short As[2 * 2 * 8192];   // [buf][half][128*64] = 64KB
    __shared__ unsigned short Bs[2 * 2 * 8192];   // 64KB (128KB total)

    const int tid  = threadIdx.x;
    const int wave = tid >> 6;
    const int lane = tid & 63;
    const int per = 16 * kspl;                   // blocks per n-tile
    const int n0  = (blockIdx.x / per) * BN;
    const int r   = blockIdx.x % per;
    const int ksp = r % kspl;
    const int m0  = (r / kspl) * BM;
    const int wm = wave >> 2;                    // 0..1
    const int wn = wave & 3;                     // 0..3

    // staging: linear LDS dest (lane*16B); global source col pre-swizzled so
    // LDS[row][c'] holds global col c' ^ ((row&7)<<4)  (T2, rule #21)
    const int srow = lane >> 3;
    const int scol = 8 * ((lane & 7) ^ (lane >> 3));
    const int kbase = ksp * ktper * BK;

    f32x4 acc[8][4];
#pragma unroll
    for (int a = 0; a < 8; ++a)
#pragma unroll
        for (int b = 0; b < 4; ++b) acc[a][b] = (f32x4){0.f, 0.f, 0.f, 0.f};

    auto stageA = [&](int buf, int h, int kt) {
        const int kk = kbase + kt * BK + scol;
#pragma unroll
        for (int c = 0; c < 2; ++c) {
            const int chunk = wave * 2 + c;      // 0..15 (8-row chunks in half)
            const unsigned short* ga =
                A + (size_t)(m0 + h * 128 + chunk * 8 + srow) * KD + kk;
            __builtin_amdgcn_global_load_lds(
                (const __attribute__((address_space(1))) unsigned int*)ga,
                (__attribute__((address_space(3))) unsigned int*)
                    &As[buf * 16384 + h * 8192 + chunk * 512], 16, 0, 0);
        }
    };
    auto stageB = [&](int buf, int h, int kt) {
        const int kk = kbase + kt * BK + scol;
#pragma unroll
        for (int c = 0; c < 2; ++c) {
            const int chunk = wave * 2 + c;
            const unsigned short* gb =
                W + (size_t)(n0 + h * 128 + chunk * 8 + srow) * KD + kk;
            __builtin_amdgcn_global_load_lds(
                (const __attribute__((address_space(1))) unsigned int*)gb,
                (__attribute__((address_space(3))) unsigned int*)
                    &Bs[buf * 16384 + h * 8192 + chunk * 512], 16, 0, 0);
        }
    };

    // prologue: stage tile 0; single free drain (loads back-to-back but only
    // once); publish.
    stageA(0, 0, 0); stageB(0, 0, 0); stageB(0, 1, 0); stageA(0, 1, 0);
    asm volatile("s_waitcnt vmcnt(0)" ::: "memory");
    SBAR;
    SCHED;

    const int rof  = lane & 15;
    const int xr   = lane & 7;
    const int kcol = lane >> 4;

    bf16x8 af[4][2], b0[2][2], b1[2][2];

    for (int t = 0; t < ktper; ++t) {
        const int cur = t & 1;
        const int nxt = cur ^ 1;
        const bool pf = (t + 1 < ktper);
        const unsigned short* Ab = &As[cur * 16384];
        const unsigned short* Bb = &Bs[cur * 16384];

        // H0 reads + early stages
        LOADAF(af, Ab);
        LOADBF(b0, Bb);
        LOADBF(b1, Bb + 8192);
        if (pf) { stageA(nxt, 0, t + 1); stageB(nxt, 0, t + 1); }
        MFMA16(af, b0, 0, 0);            // q1
        if (pf) stageB(nxt, 1, t + 1);
        MFMA16(af, b1, 0, 2);            // q2
        // H1 reads (published at BAR(t)) + last stage
        LOADAF(af, Ab + 8192);
        if (pf) stageA(nxt, 1, t + 1);
        MFMA16(af, b1, 4, 2);            // q3
        MFMA16(af, b0, 4, 0);            // q4 (register-fed)
        SCHED;
        if (pf) {
            // retire all 8 t+1 halves (youngest ~2 MFMA clusters old)
            asm volatile("s_waitcnt vmcnt(0)" ::: "memory");
            SBAR;
            SCHED;   // next tile's reads must not hoist above this point
        }
    }

    // epilogue: C/D layout col=lane&15, row=(lane>>4)*4+reg
    float* Cp = (ksp == 0) ? C : (Part + (size_t)(ksp - 1) * BATCH * DOUT);
    const int crow = (lane >> 4) * 4;
    const int ccol = lane & 15;
#pragma unroll
    for (int H = 0; H < 2; ++H)
#pragma unroll
        for (int fm = 0; fm < 4; ++fm)
#pragma unroll
            for (int F = 0; F < 2; ++F)
#pragma unroll
                for (int fn = 0; fn < 2; ++fn) {
                    const int row = m0 + H * 128 + wm * 64 + fm * 16 + crow;
                    const int col = n0 + F * 128 + wn * 32 + fn * 16 + ccol;
#pragma unroll
                    for (int rr = 0; rr < 4; ++rr)
                        Cp[(size_t)(row + rr) * DOUT + col] =
                            acc[H * 4 + fm][F * 2 + fn][rr];
                }
}

// ---------------------------------------------------------------------------
// X += sum of np partial slices, float4 vectorized (final layer only)
// ---------------------------------------------------------------------------
__global__ __launch_bounds__(256) void reduce_add(
    const float* __restrict__ P, float* __restrict__ X, int np) {
    const size_t i = ((size_t)blockIdx.x * 256 + threadIdx.x) * 4;
    f32x4 a = *(const f32x4*)(X + i);
    for (int p = 0; p < np; ++p)
        a = a + *(const f32x4*)(P + (size_t)p * BATCH * DOUT + i);
    *(f32x4*)(X + i) = a;
}

// ---------------------------------------------------------------------------
extern "C" void kernel_launch(void* const* d_in, const int* in_sizes, int n_in,
                              void* d_out, int out_size, void* d_ws, size_t ws_size,
                              hipStream_t stream) {
    const float* x        = (const float*)d_in[0];
    const float* base_w   = (const float*)d_in[1];
    const float* spline_w = (const float*)d_in[2];
    const float* scaler   = (const float*)d_in[3];
    const float* grid     = (const float*)d_in[4];
    float* out = (float*)d_out;

    char* ws = (char*)d_ws;
    unsigned short* Abf = (unsigned short*)ws;                       // 100,663,296 B
    unsigned short* Wbf = (unsigned short*)(ws + 100663296);         //  25,165,824 B
    float* xtmp = (float*)(ws + 100663296 + 25165824);               //  16,777,216 B
    float* Part = (float*)(ws + 100663296 + 25165824 + 16777216);    // up to 3x16.8MB

    // kspl=4 needs 3 partial buffers; fall back if scratch is short.
    const size_t base_need = 100663296u + 25165824u + 16777216u;
    const int kspl = (ws_size >= base_need + 3u * 16777216u) ? 4 : 2;
    const int ktper = (KD / BK) / kspl;

    for (int layer = 0; layer < 2; ++layer) {
        const float* xin = (layer == 0) ? x : xtmp;
        float* xout      = (layer == 0) ? xtmp : out;
        build_W<<<4096, 256, 0, stream>>>(base_w + (size_t)layer * DOUT * DIN,
                                          spline_w + (size_t)layer * DOUT * DIN * NC,
                                          scaler + (size_t)layer * DOUT * DIN, Wbf);
        // layer 1's build_A fuses the layer-0 split-K reduce (np = kspl-1)
        build_A<<<16384, 256, 0, stream>>>(xin, Part, (layer == 0) ? 0 : kspl - 1,
                                           grid, Abf);
        gemm_kan<<<64 * kspl, 512, 0, stream>>>(Abf, Wbf, xout, Part, kspl, ktper);
    }
    reduce_add<<<BATCH * DOUT / 1024, 256, 0, stream>>>(Part, out, kspl - 1);
}